// Round 9
// baseline (566.059 us; speedup 1.0000x reference)
//
#include <hip/hip_runtime.h>
#include <hip/hip_bf16.h>

// Diffusion decoder, algebraically factored:
//   cond_b = MLP(pe[t_b]);  q_b = Wq@(qe_b+cond_b);  qk_b = Wk^T q_b
//   logit[b,v] = qk_b . te[b,v] + qk_b.cond_b + x[b,v]       (fp32 pass over te)
//   w = softmax(logit); s_b = sum_v w te[b,v]                (bf16 pass over te)
//   new_emb_b = Wp@(Wv@(s_b+cond_b)) + bp
//   A_b = Wd1[:, :512]@new_emb_b + bd1
//   p[b,v] = Wd2 . relu(A_b + Wd1[:,512:]@te[b,v]) + bd2 + w (bf16 MFMA GEMM, fused epilogue)
//
// v9: v8 was LDS-BW-bound (64KB LDS read/chunk, 16.8M bank conflicts). A (te)
// fragments now live in AGPRs ("+a" pins, 128 AGPR — distinct from v5's failed
// "+v" arch pins; launch_bounds(512) w/o min-wave cap). te-LDS gone; K-loop LDS
// = B-only 32KB/chunk. av/wv pinned in arch regs. Also: 14 launches -> 7
// (prepw merge + fused front/back per-batch chains).

typedef __attribute__((ext_vector_type(8))) short bhalf8_t;   // 8 bf16 in 4 VGPRs
typedef __attribute__((ext_vector_type(8))) unsigned short ushort8_t;
typedef __attribute__((ext_vector_type(4))) float fx4_t;

__device__ __forceinline__ unsigned short f2bf(float f) {
  unsigned int u = __float_as_uint(f);
  unsigned int r = (u + 0x7FFFu + ((u >> 16) & 1u)) >> 16;  // RNE
  return (unsigned short)r;
}
__device__ __forceinline__ float bf2f(unsigned short h) {
  return __uint_as_float((unsigned int)h << 16);
}

__device__ __forceinline__ float wave_sum64(float s) {
#pragma unroll
  for (int o = 32; o; o >>= 1) s += __shfl_xor(s, o, 64);
  return s;
}

// ---------------- P: all weight prep in ONE launch ----------------
// z 0..4 : 512x512 transposes (y<16)      z=5 : Wd1[:, :512] -> Wd1aT [512][1024]
// z=6    : convw  Wd1[:,512:] -> bf16 fragment-major 16KB chunks (y<16)
__global__ __launch_bounds__(256) void prepw_kernel(
    const float* __restrict__ Wt1, const float* __restrict__ Wt2, const float* __restrict__ Wq,
    const float* __restrict__ Wv, const float* __restrict__ Wp, const float* __restrict__ Wd1,
    float* __restrict__ Wt1T, float* __restrict__ Wt2T, float* __restrict__ WqT,
    float* __restrict__ WvT, float* __restrict__ WpT, float* __restrict__ Wd1aT,
    unsigned short* __restrict__ wsW) {
  const int z = blockIdx.z;
  if (z == 6) {
    if (blockIdx.y >= 16) return;
    const int g = (blockIdx.y * 16 + blockIdx.x) * 256 + threadIdx.x;  // 0..65535
    const int lane = g & 63;
    const int kc = (g >> 6) & 1;
    const int nhn = (g >> 7) & 7;
    const int ks = (g >> 10) & 7;
    const int nc = g >> 13;
    const int j = nc * 128 + (nhn >> 1) * 32 + (nhn & 1) * 16 + (lane & 15);
    const int k = ks * 64 + kc * 32 + (lane >> 4) * 8;
    const float* src = Wd1 + (size_t)j * 1024 + 512 + k;
    float4 f0 = *(const float4*)src;
    float4 f1 = *(const float4*)(src + 4);
    ushort4 h0 = make_ushort4(f2bf(f0.x), f2bf(f0.y), f2bf(f0.z), f2bf(f0.w));
    ushort4 h1 = make_ushort4(f2bf(f1.x), f2bf(f1.y), f2bf(f1.z), f2bf(f1.w));
    ushort4* dst = (ushort4*)((char*)wsW + (size_t)g * 16);
    dst[0] = h0;
    dst[1] = h1;
    return;
  }
  __shared__ float t[32][33];
  const int tx = threadIdx.x & 31, ty = threadIdx.x >> 5;
  const int c0 = blockIdx.x * 32, r0 = blockIdx.y * 32;
  if (z == 5) {  // Wd1 first half: src [1024][1024] cols 0..511 -> dst [512][1024]
    const float* src = Wd1;
    float* dst = Wd1aT;
#pragma unroll
    for (int i = 0; i < 32; i += 8)
      t[ty + i][tx] = src[(size_t)(r0 + ty + i) * 1024 + c0 + tx];
    __syncthreads();
#pragma unroll
    for (int i = 0; i < 32; i += 8)
      dst[(size_t)(c0 + ty + i) * 1024 + r0 + tx] = t[tx][ty + i];
    return;
  }
  if (blockIdx.y >= 16) return;
  const float* src;
  float* dst;
  switch (z) {
    case 0: src = Wt1; dst = Wt1T; break;
    case 1: src = Wt2; dst = Wt2T; break;
    case 2: src = Wq; dst = WqT; break;
    case 3: src = Wv; dst = WvT; break;
    default: src = Wp; dst = WpT; break;
  }
#pragma unroll
  for (int i = 0; i < 32; i += 8)
    t[ty + i][tx] = src[(size_t)(r0 + ty + i) * 512 + c0 + tx];
  __syncthreads();
#pragma unroll
  for (int i = 0; i < 32; i += 8)
    dst[(size_t)(c0 + ty + i) * 512 + r0 + tx] = t[tx][ty + i];
}

// ---------------- F: fused front chain, one block per batch ----------------
// pe -> hid=silu(Wt1..) -> cond -> q=Wq(qe+cond) -> qk=Wk^T q -> cb=qk.cond
__global__ __launch_bounds__(512) void front_kernel(
    const int* __restrict__ timesteps, const float* __restrict__ qe,
    const float* __restrict__ Wt1T, const float* __restrict__ bt1,
    const float* __restrict__ Wt2T, const float* __restrict__ bt2,
    const float* __restrict__ WqT, const float* __restrict__ Wk,
    float* __restrict__ cond_out, float* __restrict__ qk_out, float* __restrict__ cb_out) {
  __shared__ __attribute__((aligned(16))) float v0[512], v1[512], v2[512];
  __shared__ float rd[8];
  const int b = blockIdx.x, tid = threadIdx.x;
  if (tid < 256) {
    const int ts = timesteps[b];
    const float NEG = -9.2103403719761836f / 512.f;  // -ln(10000)/512
    float dv = expf((float)(2 * tid) * NEG);
    float ang = (float)ts * dv;
    v0[2 * tid] = sinf(ang);
    v0[2 * tid + 1] = cosf(ang);
  }
  __syncthreads();
  // hid -> v1
  {
    float s0 = 0.f, s1 = 0.f, s2 = 0.f, s3 = 0.f;
#pragma unroll 4
    for (int k = 0; k < 512; k += 4) {
      s0 = fmaf(v0[k], Wt1T[(size_t)k * 512 + tid], s0);
      s1 = fmaf(v0[k + 1], Wt1T[(size_t)(k + 1) * 512 + tid], s1);
      s2 = fmaf(v0[k + 2], Wt1T[(size_t)(k + 2) * 512 + tid], s2);
      s3 = fmaf(v0[k + 3], Wt1T[(size_t)(k + 3) * 512 + tid], s3);
    }
    float s = (s0 + s1) + (s2 + s3) + bt1[tid];
    s = s / (1.f + expf(-s));  // silu
    v1[tid] = s;
  }
  __syncthreads();
  // cond -> v0 (+global)
  {
    float s0 = 0.f, s1 = 0.f, s2 = 0.f, s3 = 0.f;
#pragma unroll 4
    for (int k = 0; k < 512; k += 4) {
      s0 = fmaf(v1[k], Wt2T[(size_t)k * 512 + tid], s0);
      s1 = fmaf(v1[k + 1], Wt2T[(size_t)(k + 1) * 512 + tid], s1);
      s2 = fmaf(v1[k + 2], Wt2T[(size_t)(k + 2) * 512 + tid], s2);
      s3 = fmaf(v1[k + 3], Wt2T[(size_t)(k + 3) * 512 + tid], s3);
    }
    float s = (s0 + s1) + (s2 + s3) + bt2[tid];
    v0[tid] = s;
    cond_out[(size_t)b * 512 + tid] = s;
    v1[tid] = qe[(size_t)b * 512 + tid] + s;  // arow for q
  }
  __syncthreads();
  // q -> v2
  {
    float s0 = 0.f, s1 = 0.f, s2 = 0.f, s3 = 0.f;
#pragma unroll 4
    for (int k = 0; k < 512; k += 4) {
      s0 = fmaf(v1[k], WqT[(size_t)k * 512 + tid], s0);
      s1 = fmaf(v1[k + 1], WqT[(size_t)(k + 1) * 512 + tid], s1);
      s2 = fmaf(v1[k + 2], WqT[(size_t)(k + 2) * 512 + tid], s2);
      s3 = fmaf(v1[k + 3], WqT[(size_t)(k + 3) * 512 + tid], s3);
    }
    v2[tid] = (s0 + s1) + (s2 + s3);
  }
  __syncthreads();
  // qk (e = tid) + cb reduce
  {
    float s0 = 0.f, s1 = 0.f, s2 = 0.f, s3 = 0.f;
#pragma unroll 4
    for (int d = 0; d < 512; d += 4) {
      s0 = fmaf(v2[d], Wk[(size_t)d * 512 + tid], s0);
      s1 = fmaf(v2[d + 1], Wk[(size_t)(d + 1) * 512 + tid], s1);
      s2 = fmaf(v2[d + 2], Wk[(size_t)(d + 2) * 512 + tid], s2);
      s3 = fmaf(v2[d + 3], Wk[(size_t)(d + 3) * 512 + tid], s3);
    }
    float qkv = (s0 + s1) + (s2 + s3);
    qk_out[(size_t)b * 512 + tid] = qkv;
    float p = wave_sum64(qkv * v0[tid]);
    if ((tid & 63) == 0) rd[tid >> 6] = p;
  }
  __syncthreads();
  if (tid == 0) {
    float c = 0.f;
#pragma unroll
    for (int w = 0; w < 8; ++w) c += rd[w];
    cb_out[b] = c;
  }
}

// ---------------- B: fused back chain, one block per batch ----------------
// s = cond + sum spart -> u = Wv s -> ne = Wp u + bp -> A = Wd1a ne + bd1
__global__ __launch_bounds__(512) void back_kernel(
    const float* __restrict__ spart, const float* __restrict__ cond,
    const float* __restrict__ WvT, const float* __restrict__ WpT, const float* __restrict__ bp,
    const float* __restrict__ Wd1aT, const float* __restrict__ bd1, float* __restrict__ Abuf) {
  __shared__ __attribute__((aligned(16))) float v0[512], v1[512];
  const int b = blockIdx.x, tid = threadIdx.x;
  {
    float s = cond[(size_t)b * 512 + tid];
#pragma unroll
    for (int q = 0; q < 8; ++q) s += spart[((size_t)b * 8 + q) * 512 + tid];
    v0[tid] = s;
  }
  __syncthreads();
  {
    float s0 = 0.f, s1 = 0.f, s2 = 0.f, s3 = 0.f;
#pragma unroll 4
    for (int k = 0; k < 512; k += 4) {
      s0 = fmaf(v0[k], WvT[(size_t)k * 512 + tid], s0);
      s1 = fmaf(v0[k + 1], WvT[(size_t)(k + 1) * 512 + tid], s1);
      s2 = fmaf(v0[k + 2], WvT[(size_t)(k + 2) * 512 + tid], s2);
      s3 = fmaf(v0[k + 3], WvT[(size_t)(k + 3) * 512 + tid], s3);
    }
    v1[tid] = (s0 + s1) + (s2 + s3);
  }
  __syncthreads();
  {
    float s0 = 0.f, s1 = 0.f, s2 = 0.f, s3 = 0.f;
#pragma unroll 4
    for (int k = 0; k < 512; k += 4) {
      s0 = fmaf(v1[k], WpT[(size_t)k * 512 + tid], s0);
      s1 = fmaf(v1[k + 1], WpT[(size_t)(k + 1) * 512 + tid], s1);
      s2 = fmaf(v1[k + 2], WpT[(size_t)(k + 2) * 512 + tid], s2);
      s3 = fmaf(v1[k + 3], WpT[(size_t)(k + 3) * 512 + tid], s3);
    }
    v0[tid] = (s0 + s1) + (s2 + s3) + bp[tid];
  }
  __syncthreads();
  {
    float a0 = 0.f, a1 = 0.f, b0 = 0.f, b1 = 0.f;
#pragma unroll 2
    for (int k = 0; k < 512; k += 2) {
      float x0 = v0[k], x1 = v0[k + 1];
      a0 = fmaf(x0, Wd1aT[(size_t)k * 1024 + tid], a0);
      a1 = fmaf(x1, Wd1aT[(size_t)(k + 1) * 1024 + tid], a1);
      b0 = fmaf(x0, Wd1aT[(size_t)k * 1024 + 512 + tid], b0);
      b1 = fmaf(x1, Wd1aT[(size_t)(k + 1) * 1024 + 512 + tid], b1);
    }
    Abuf[(size_t)b * 1024 + tid] = a0 + a1 + bd1[tid];
    Abuf[(size_t)b * 1024 + 512 + tid] = b0 + b1 + bd1[512 + tid];
  }
}

// ---------------- K3: logits (fp32 dot pass over te; optional bf16 te emit) ----------------
__global__ __launch_bounds__(256) void logits_kernel(
    const float* __restrict__ te, const float* __restrict__ qk,
    const float* __restrict__ constb, const float* __restrict__ x,
    float* __restrict__ logits, unsigned short* __restrict__ te16, int w16) {
  const int wave = threadIdx.x >> 6, lane = threadIdx.x & 63;
  const size_t r = (size_t)blockIdx.x * 4 + wave;
  const int b = (int)(r >> 10);
  const float4* t4 = (const float4*)(te + r * 512);
  const float4* q4 = (const float4*)(qk + (size_t)b * 512);
  float4 a0 = t4[lane], a1 = t4[lane + 64];
  float4 c0 = q4[lane], c1 = q4[lane + 64];
  float s = a0.x * c0.x + a0.y * c0.y + a0.z * c0.z + a0.w * c0.w +
            a1.x * c1.x + a1.y * c1.y + a1.z * c1.z + a1.w * c1.w;
  s = wave_sum64(s);
  if (w16) {
    ushort4 h0 = make_ushort4(f2bf(a0.x), f2bf(a0.y), f2bf(a0.z), f2bf(a0.w));
    ushort4 h1 = make_ushort4(f2bf(a1.x), f2bf(a1.y), f2bf(a1.z), f2bf(a1.w));
    *(ushort4*)(te16 + r * 512 + lane * 4) = h0;
    *(ushort4*)(te16 + r * 512 + 256 + lane * 4) = h1;
  }
  if (lane == 0) logits[r] = s + constb[b] + x[r];
}

// ---------------- K4: softmax per batch; also init out = w + bd2 ----------------
__global__ __launch_bounds__(256) void softmax_kernel(
    const float* __restrict__ logits, const float* __restrict__ bd2,
    float* __restrict__ weight, float* __restrict__ out) {
  __shared__ float sm[4];
  const int b = blockIdx.x, tid = threadIdx.x;
  const int wave = tid >> 6, lane = tid & 63;
  float4 l4 = ((const float4*)(logits + (size_t)b * 1024))[tid];
  float m = fmaxf(fmaxf(l4.x, l4.y), fmaxf(l4.z, l4.w));
#pragma unroll
  for (int o = 32; o; o >>= 1) m = fmaxf(m, __shfl_xor(m, o, 64));
  if (lane == 0) sm[wave] = m;
  __syncthreads();
  float M = fmaxf(fmaxf(sm[0], sm[1]), fmaxf(sm[2], sm[3]));
  __syncthreads();
  float e0 = expf(l4.x - M), e1 = expf(l4.y - M), e2 = expf(l4.z - M), e3 = expf(l4.w - M);
  float ssum = wave_sum64(e0 + e1 + e2 + e3);
  if (lane == 0) sm[wave] = ssum;
  __syncthreads();
  float inv = 1.f / (sm[0] + sm[1] + sm[2] + sm[3]);
  float c = bd2[0];
  float4 w4 = make_float4(e0 * inv, e1 * inv, e2 * inv, e3 * inv);
  ((float4*)(weight + (size_t)b * 1024))[tid] = w4;
  ((float4*)(out + (size_t)b * 1024))[tid] = make_float4(w4.x + c, w4.y + c, w4.z + c, w4.w + c);
}

// ---------------- K5a: spart[(b,vq)][d] = sum_{v in chunk} w * te  (fp32 input) ----------------
__global__ __launch_bounds__(256) void wsum32_kernel(const float* __restrict__ te,
                                                     const float* __restrict__ weight,
                                                     float* __restrict__ spart) {
  __shared__ float wl[128];
  const int b = blockIdx.x >> 3, vq = blockIdx.x & 7;
  const int tid = threadIdx.x;
  if (tid < 128) wl[tid] = weight[(size_t)b * 1024 + vq * 128 + tid];
  __syncthreads();
  const float* tb = te + ((size_t)b * 1024 + (size_t)vq * 128) * 512;
  float s0 = 0.f, s1 = 0.f;
#pragma unroll 4
  for (int v = 0; v < 128; ++v) {
    float w = wl[v];
    s0 += w * tb[(size_t)v * 512 + tid];
    s1 += w * tb[(size_t)v * 512 + 256 + tid];
  }
  spart[(size_t)blockIdx.x * 512 + tid] = s0;
  spart[(size_t)blockIdx.x * 512 + 256 + tid] = s1;
}

// ---------------- K5a': same from bf16 te ----------------
__global__ __launch_bounds__(256) void wsum16_kernel(const unsigned short* __restrict__ te16,
                                                     const float* __restrict__ weight,
                                                     float* __restrict__ spart) {
  __shared__ float wl[128];
  __shared__ float red[4][512];
  const int b = blockIdx.x >> 3, vq = blockIdx.x & 7;
  const int tid = threadIdx.x;
  if (tid < 128) wl[tid] = weight[(size_t)b * 1024 + vq * 128 + tid];
  __syncthreads();
  const int g = tid & 63, vh = tid >> 6;
  const unsigned short* base =
      te16 + ((size_t)b * 1024 + vq * 128 + vh * 32) * 512 + g * 8;
  float acc[8] = {};
  for (int v = 0; v < 32; ++v) {
    float w = wl[vh * 32 + v];
    ushort8_t h = *(const ushort8_t*)(base + (size_t)v * 512);
#pragma unroll
    for (int i = 0; i < 8; ++i) acc[i] += w * bf2f(h[i]);
  }
#pragma unroll
  for (int i = 0; i < 8; ++i) red[vh][g * 8 + i] = acc[i];
  __syncthreads();
  for (int d = tid; d < 512; d += 256)
    spart[(size_t)blockIdx.x * 512 + d] =
        red[0][d] + red[1][d] + red[2][d] + red[3][d];
}

// ---------------- K6: decoder GEMM + fused epilogue (v9) ----------------
// 2048 blocks x 512 thr (8 waves = 2mh x 4nh). Block: 64 rows x 1024 cols, K=512.
// A (te16) fragments in AGPRs ("+a" pins, 32 frags = 128 AGPR), loaded once.
// W: 64 chunks of 16KB, LDS ring 4x16KB via global_load_lds, depth-3 counted
// vmcnt, one barrier per chunk. LDS/chunk = B-only 32KB (was 64KB in v8).
#define GLD16(g, l)                                                              \
  __builtin_amdgcn_global_load_lds((const __attribute__((address_space(1))) void*)(g), \
                                   (__attribute__((address_space(3))) void*)(l), 16, 0, 0)

template <int USE16>
__global__ __launch_bounds__(512) void decoder_kernel(
    const float* __restrict__ te, const unsigned short* __restrict__ te16,
    const unsigned short* __restrict__ wsW, const float* __restrict__ A,
    const float* __restrict__ Wd2, float* __restrict__ out) {
  extern __shared__ char lds[];   // W ring 4x16384 | red 2048
  char* ring = lds;

  const int tid = threadIdx.x;
  const int wave = tid >> 6, lane = tid & 63;
  const int lhi = lane >> 4, llo = lane & 15;
  const int mh = wave >> 2, nh = wave & 3;
  const size_t row0 = (size_t)blockIdx.x * 64;
  const int b = (int)(blockIdx.x >> 4);

  // ---- W staging: chunk c -> ring slot (c&3); 2 GLD16 per thread ----
  auto stage = [&](int c) {
    const char* src = (const char*)wsW + (size_t)c * 16384 + wave * 1024 + lane * 16;
    char* dst = ring + (c & 3) * 16384 + wave * 1024;  // HW appends lane*16
    GLD16(src, dst);
    GLD16(src + 8192, dst + 8192);
  };
  stage(0); stage(1); stage(2);

  // ---- A fragments -> AGPRs: a[m][s], s = ks*2+kc, k = s*32 + lhi*8 + i ----
  bhalf8_t a[2][16];
  if (USE16) {
#pragma unroll
    for (int m = 0; m < 2; ++m) {
      const char* rowp = (const char*)te16 + (row0 + mh * 32 + m * 16 + llo) * 1024 + lhi * 16;
#pragma unroll
      for (int s = 0; s < 16; ++s) a[m][s] = *(const bhalf8_t*)(rowp + s * 64);
    }
  } else {
#pragma unroll
    for (int m = 0; m < 2; ++m) {
      const char* rowp = (const char*)te + (row0 + mh * 32 + m * 16 + llo) * 2048 + lhi * 32;
#pragma unroll
      for (int s = 0; s < 16; ++s) {
        float4 f0 = *(const float4*)(rowp + s * 128);
        float4 f1 = *(const float4*)(rowp + s * 128 + 16);
        bhalf8_t h;
        h[0] = (short)f2bf(f0.x); h[1] = (short)f2bf(f0.y);
        h[2] = (short)f2bf(f0.z); h[3] = (short)f2bf(f0.w);
        h[4] = (short)f2bf(f1.x); h[5] = (short)f2bf(f1.y);
        h[6] = (short)f2bf(f1.z); h[7] = (short)f2bf(f1.w);
        a[m][s] = h;
      }
    }
  }

  // ---- epilogue scalars hoisted to arch regs ----
  float av[8][2], wv[8][2];
  {
    const float* A_g = A + (size_t)b * 1024;
#pragma unroll
    for (int nc = 0; nc < 8; ++nc) {
      const int jb = nc * 128 + nh * 32 + llo;
      av[nc][0] = A_g[jb];
      av[nc][1] = A_g[jb + 16];
      wv[nc][0] = Wd2[jb];
      wv[nc][1] = Wd2[jb + 16];
    }
  }

  // ---- pins: A into AGPR class (does not consume the arch budget), av/wv arch ----
#pragma unroll
  for (int m = 0; m < 2; ++m)
#pragma unroll
    for (int s = 0; s < 16; ++s) asm volatile("" : "+a"(a[m][s]));
#pragma unroll
  for (int nc = 0; nc < 8; ++nc)
    asm volatile("" : "+v"(av[nc][0]), "+v"(av[nc][1]), "+v"(wv[nc][0]), "+v"(wv[nc][1]));

  __syncthreads();

  fx4_t acc[2][2];
  const fx4_t zf = {0.f, 0.f, 0.f, 0.f};
  float pacc[2][4] = {};

#pragma unroll
  for (int nc = 0; nc < 8; ++nc) {
#pragma unroll
    for (int ks = 0; ks < 8; ++ks) {
      const int c = nc * 8 + ks;
      if (c <= 61)      asm volatile("s_waitcnt vmcnt(4)" ::: "memory");
      else if (c == 62) asm volatile("s_waitcnt vmcnt(2)" ::: "memory");
      else              asm volatile("s_waitcnt vmcnt(0)" ::: "memory");
      __builtin_amdgcn_s_barrier();
      __builtin_amdgcn_sched_barrier(0);
      if (ks == 0) { acc[0][0] = zf; acc[0][1] = zf; acc[1][0] = zf; acc[1][1] = zf; }
      const char* wb = ring + (c & 3) * 16384 + nh * 4096 + lane * 16;
      bhalf8_t b00 = *(const bhalf8_t*)(wb);
      bhalf8_t b01 = *(const bhalf8_t*)(wb + 1024);
      bhalf8_t b10 = *(const bhalf8_t*)(wb + 2048);
      bhalf8_t b11 = *(const bhalf8_t*)(wb + 3072);
      acc[0][0] = __builtin_amdgcn_mfma_f32_16x16x32_bf16(a[0][ks * 2 + 0], b00, acc[0][0], 0, 0, 0);
      acc[0][0] = __builtin_amdgcn_mfma_f32_16x16x32_bf16(a[0][ks * 2 + 1], b01, acc[0][0], 0, 0, 0);
      acc[0][1] = __builtin_amdgcn_mfma_f32_16x16x32_bf16(a[0][ks * 2 + 0], b10, acc[0][1], 0, 0, 0);
      acc[0][1] = __builtin_amdgcn_mfma_f32_16x16x32_bf16(a[0][ks * 2 + 1], b11, acc[0][1], 0, 0, 0);
      acc[1][0] = __builtin_amdgcn_mfma_f32_16x16x32_bf16(a[1][ks * 2 + 0], b00, acc[1][0], 0, 0, 0);
      acc[1][0] = __builtin_amdgcn_mfma_f32_16x16x32_bf16(a[1][ks * 2 + 1], b01, acc[1][0], 0, 0, 0);
      acc[1][1] = __builtin_amdgcn_mfma_f32_16x16x32_bf16(a[1][ks * 2 + 0], b10, acc[1][1], 0, 0, 0);
      acc[1][1] = __builtin_amdgcn_mfma_f32_16x16x32_bf16(a[1][ks * 2 + 1], b11, acc[1][1], 0, 0, 0);
      if (c <= 60) stage(c + 3);
      if (ks == 7) {  // epilogue for this 128-col chunk (registers only)
#pragma unroll
        for (int n = 0; n < 2; ++n)
#pragma unroll
          for (int m = 0; m < 2; ++m)
#pragma unroll
            for (int rg = 0; rg < 4; ++rg)
              pacc[m][rg] += fmaxf(acc[m][n][rg] + av[nc][n], 0.f) * wv[nc][n];
      }
    }
  }

  // ---- reduction (red region separate from ring) ----
  __syncthreads();
  float* red = (float*)(lds + 65536);
#pragma unroll
  for (int m = 0; m < 2; ++m)
#pragma unroll
    for (int rg = 0; rg < 4; ++rg) {
      float sv = pacc[m][rg];
      sv += __shfl_xor(sv, 1, 64);
      sv += __shfl_xor(sv, 2, 64);
      sv += __shfl_xor(sv, 4, 64);
      sv += __shfl_xor(sv, 8, 64);
      if (llo == 0) red[nh * 64 + mh * 32 + m * 16 + lhi * 4 + rg] = sv;
    }
  __syncthreads();
  if (tid < 64) {
    float s = red[tid] + red[64 + tid] + red[128 + tid] + red[192 + tid];
    out[row0 + tid] += s;  // out pre-initialized to w + bd2; rows exclusive per block
  }
}

// ---------------- launch ----------------
extern "C" void kernel_launch(void* const* d_in, const int* in_sizes, int n_in,
                              void* d_out, int out_size, void* d_ws, size_t ws_size,
                              hipStream_t stream) {
  const float* x = (const float*)d_in[0];
  const int* tsteps = (const int*)d_in[1];
  const float* qe = (const float*)d_in[2];
  const float* te = (const float*)d_in[3];
  const float* Wq = (const float*)d_in[4];
  const float* Wk = (const float*)d_in[5];
  const float* Wv = (const float*)d_in[6];
  const float* Wp = (const float*)d_in[7];
  const float* bp = (const float*)d_in[8];
  const float* Wt1 = (const float*)d_in[9];
  const float* bt1 = (const float*)d_in[10];
  const float* Wt2 = (const float*)d_in[11];
  const float* bt2 = (const float*)d_in[12];
  const float* Wd1 = (const float*)d_in[13];
  const float* bd1 = (const float*)d_in[14];
  const float* Wd2 = (const float*)d_in[15];
  const float* bd2 = (const float*)d_in[16];
  float* out = (float*)d_out;

  char* ws = (char*)d_ws;
  unsigned short* wsW = (unsigned short*)(ws + 0);     // 1 MB
  float* Wt1T = (float*)(ws + 1048576);                // 1 MB each
  float* Wt2T = (float*)(ws + 2097152);
  float* WqT = (float*)(ws + 3145728);
  float* WvT = (float*)(ws + 4194304);
  float* WpT = (float*)(ws + 5242880);
  float* Wd1aT = (float*)(ws + 6291456);               // 2 MB [512][1024]
  float* cond = (float*)(ws + 8388608);                // 256 KB
  float* qk = (float*)(ws + 8650752);
  float* cb = (float*)(ws + 9961472);                  // 4 KB slot
  float* logits = (float*)(ws + 9965568);              // 512 KB
  float* wgt = (float*)(ws + 10489856);                // 512 KB
  float* spart = (float*)(ws + 11014144);              // 2 MB [128*8][512]
  float* Abuf = (float*)(ws + 13111296);               // 512 KB
  const size_t TE16_OFF = 14680064;                    // 14 MB
  const size_t TE16_BYTES = (size_t)128 * 1024 * 512 * 2;  // 128 MB
  unsigned short* te16 = (unsigned short*)(ws + TE16_OFF);
  const int use16 = (ws_size >= TE16_OFF + TE16_BYTES) ? 1 : 0;

  // 1: all weight prep (transposes + decoder W pre-pack)
  prepw_kernel<<<dim3(16, 32, 7), 256, 0, stream>>>(Wt1, Wt2, Wq, Wv, Wp, Wd1,
                                                    Wt1T, Wt2T, WqT, WvT, WpT, Wd1aT, wsW);
  // 2: fused front chain (cond, qk, cb)
  front_kernel<<<128, 512, 0, stream>>>(tsteps, qe, Wt1T, bt1, Wt2T, bt2, WqT, Wk,
                                        cond, qk, cb);
  // 3: logits (+te16 emit)
  logits_kernel<<<32768, 256, 0, stream>>>(te, qk, cb, x, logits, te16, use16);
  // 4: softmax (writes wgt; inits out = w + bd2)
  softmax_kernel<<<128, 256, 0, stream>>>(logits, bd2, wgt, out);
  // 5: weighted te sum partials
  if (use16)
    wsum16_kernel<<<1024, 256, 0, stream>>>(te16, wgt, spart);
  else
    wsum32_kernel<<<1024, 256, 0, stream>>>(te, wgt, spart);
  // 6: fused back chain (new_emb -> A)
  back_kernel<<<128, 512, 0, stream>>>(spart, cond, WvT, WpT, bp, Wd1aT, bd1, Abuf);
  // 7: decoder GEMM + epilogue
  if (use16) {
    (void)hipFuncSetAttribute((const void*)decoder_kernel<1>,
                              hipFuncAttributeMaxDynamicSharedMemorySize, 67584);
    decoder_kernel<1><<<2048, 512, 67584, stream>>>(te, te16, wsW, Abuf, Wd2, out);
  } else {
    (void)hipFuncSetAttribute((const void*)decoder_kernel<0>,
                              hipFuncAttributeMaxDynamicSharedMemorySize, 67584);
    decoder_kernel<0><<<2048, 512, 67584, stream>>>(te, te16, wsW, Abuf, Wd2, out);
  }
}

// Round 10
// 535.014 us; speedup vs baseline: 1.0580x; 1.0580x over previous
//
#include <hip/hip_runtime.h>
#include <hip/hip_bf16.h>

// Diffusion decoder, algebraically factored:
//   cond_b = MLP(pe[t_b]);  q_b = Wq@(qe_b+cond_b);  qk_b = Wk^T q_b
//   logit[b,v] = qk_b . te[b,v] + qk_b.cond_b + x[b,v]       (fp32 pass over te)
//   w = softmax(logit); s_b = sum_v w te[b,v]                (bf16 pass over te)
//   new_emb_b = Wp@(Wv@(s_b+cond_b)) + bp
//   A_b = Wd1[:, :512]@new_emb_b + bd1
//   p[b,v] = Wd2 . relu(A_b + Wd1[:,512:]@te[b,v]) + bd2 + w (bf16 MFMA GEMM, fused epilogue)
//
// v10 decoder: register-resident-A abandoned (v5/v9 evidence). v8 base
// (A-in-LDS, no spill) with its LDS bottleneck fixed: wave tile 64x64
// (acc[4][4] -> AGPR; arch live ~100 < 128, audited), B global->reg
// wave-private dbuf (no B-LDS, no A nh-duplication: block LDS reads 4MB->1MB),
// ZERO barriers in the K-loop. A staged once via global_load_lds, XOR-swizzled.

typedef __attribute__((ext_vector_type(8))) short bhalf8_t;   // 8 bf16 in 4 VGPRs
typedef __attribute__((ext_vector_type(8))) unsigned short ushort8_t;
typedef __attribute__((ext_vector_type(4))) float fx4_t;

__device__ __forceinline__ unsigned short f2bf(float f) {
  unsigned int u = __float_as_uint(f);
  unsigned int r = (u + 0x7FFFu + ((u >> 16) & 1u)) >> 16;  // RNE
  return (unsigned short)r;
}
__device__ __forceinline__ float bf2f(unsigned short h) {
  return __uint_as_float((unsigned int)h << 16);
}

__device__ __forceinline__ float wave_sum64(float s) {
#pragma unroll
  for (int o = 32; o; o >>= 1) s += __shfl_xor(s, o, 64);
  return s;
}

// ---------------- P: all weight prep in ONE launch ----------------
// z 0..4 : 512x512 transposes (y<16)      z=5 : Wd1[:, :512] -> Wd1aT [512][1024]
// z=6    : convw  Wd1[:,512:] -> bf16 fragment-major 1KB frags (y<16)
//          fragid = ((p*8+w)*16+s)*4+n ; frag holds W[j][512+k..+8] with
//          j = p*512 + w*64 + n*16 + (lane&15), k = s*32 + (lane>>4)*8
__global__ __launch_bounds__(256) void prepw_kernel(
    const float* __restrict__ Wt1, const float* __restrict__ Wt2, const float* __restrict__ Wq,
    const float* __restrict__ Wv, const float* __restrict__ Wp, const float* __restrict__ Wd1,
    float* __restrict__ Wt1T, float* __restrict__ Wt2T, float* __restrict__ WqT,
    float* __restrict__ WvT, float* __restrict__ WpT, float* __restrict__ Wd1aT,
    unsigned short* __restrict__ wsW) {
  const int z = blockIdx.z;
  if (z == 6) {
    if (blockIdx.y >= 16) return;
    const int g = (blockIdx.y * 16 + blockIdx.x) * 256 + threadIdx.x;  // 0..65535
    const int lane = g & 63;
    const int fragid = g >> 6;
    const int n = fragid & 3;
    const int s = (fragid >> 2) & 15;
    const int w = (fragid >> 6) & 7;
    const int p = fragid >> 9;
    const int j = p * 512 + w * 64 + n * 16 + (lane & 15);
    const int k = s * 32 + (lane >> 4) * 8;
    const float* src = Wd1 + (size_t)j * 1024 + 512 + k;
    float4 f0 = *(const float4*)src;
    float4 f1 = *(const float4*)(src + 4);
    ushort4 h0 = make_ushort4(f2bf(f0.x), f2bf(f0.y), f2bf(f0.z), f2bf(f0.w));
    ushort4 h1 = make_ushort4(f2bf(f1.x), f2bf(f1.y), f2bf(f1.z), f2bf(f1.w));
    ushort4* dst = (ushort4*)((char*)wsW + (size_t)g * 16);
    dst[0] = h0;
    dst[1] = h1;
    return;
  }
  __shared__ float t[32][33];
  const int tx = threadIdx.x & 31, ty = threadIdx.x >> 5;
  const int c0 = blockIdx.x * 32, r0 = blockIdx.y * 32;
  if (z == 5) {  // Wd1 first half: src [1024][1024] cols 0..511 -> dst [512][1024]
    const float* src = Wd1;
    float* dst = Wd1aT;
#pragma unroll
    for (int i = 0; i < 32; i += 8)
      t[ty + i][tx] = src[(size_t)(r0 + ty + i) * 1024 + c0 + tx];
    __syncthreads();
#pragma unroll
    for (int i = 0; i < 32; i += 8)
      dst[(size_t)(c0 + ty + i) * 1024 + r0 + tx] = t[tx][ty + i];
    return;
  }
  if (blockIdx.y >= 16) return;
  const float* src;
  float* dst;
  switch (z) {
    case 0: src = Wt1; dst = Wt1T; break;
    case 1: src = Wt2; dst = Wt2T; break;
    case 2: src = Wq; dst = WqT; break;
    case 3: src = Wv; dst = WvT; break;
    default: src = Wp; dst = WpT; break;
  }
#pragma unroll
  for (int i = 0; i < 32; i += 8)
    t[ty + i][tx] = src[(size_t)(r0 + ty + i) * 512 + c0 + tx];
  __syncthreads();
#pragma unroll
  for (int i = 0; i < 32; i += 8)
    dst[(size_t)(c0 + ty + i) * 512 + r0 + tx] = t[tx][ty + i];
}

// ---------------- F: fused front chain, one block per batch ----------------
__global__ __launch_bounds__(512) void front_kernel(
    const int* __restrict__ timesteps, const float* __restrict__ qe,
    const float* __restrict__ Wt1T, const float* __restrict__ bt1,
    const float* __restrict__ Wt2T, const float* __restrict__ bt2,
    const float* __restrict__ WqT, const float* __restrict__ Wk,
    float* __restrict__ cond_out, float* __restrict__ qk_out, float* __restrict__ cb_out) {
  __shared__ __attribute__((aligned(16))) float v0[512], v1[512], v2[512];
  __shared__ float rd[8];
  const int b = blockIdx.x, tid = threadIdx.x;
  if (tid < 256) {
    const int ts = timesteps[b];
    const float NEG = -9.2103403719761836f / 512.f;  // -ln(10000)/512
    float dv = expf((float)(2 * tid) * NEG);
    float ang = (float)ts * dv;
    v0[2 * tid] = sinf(ang);
    v0[2 * tid + 1] = cosf(ang);
  }
  __syncthreads();
  {
    float s0 = 0.f, s1 = 0.f, s2 = 0.f, s3 = 0.f;
#pragma unroll 4
    for (int k = 0; k < 512; k += 4) {
      s0 = fmaf(v0[k], Wt1T[(size_t)k * 512 + tid], s0);
      s1 = fmaf(v0[k + 1], Wt1T[(size_t)(k + 1) * 512 + tid], s1);
      s2 = fmaf(v0[k + 2], Wt1T[(size_t)(k + 2) * 512 + tid], s2);
      s3 = fmaf(v0[k + 3], Wt1T[(size_t)(k + 3) * 512 + tid], s3);
    }
    float s = (s0 + s1) + (s2 + s3) + bt1[tid];
    s = s / (1.f + expf(-s));  // silu
    v1[tid] = s;
  }
  __syncthreads();
  {
    float s0 = 0.f, s1 = 0.f, s2 = 0.f, s3 = 0.f;
#pragma unroll 4
    for (int k = 0; k < 512; k += 4) {
      s0 = fmaf(v1[k], Wt2T[(size_t)k * 512 + tid], s0);
      s1 = fmaf(v1[k + 1], Wt2T[(size_t)(k + 1) * 512 + tid], s1);
      s2 = fmaf(v1[k + 2], Wt2T[(size_t)(k + 2) * 512 + tid], s2);
      s3 = fmaf(v1[k + 3], Wt2T[(size_t)(k + 3) * 512 + tid], s3);
    }
    float s = (s0 + s1) + (s2 + s3) + bt2[tid];
    v0[tid] = s;
    cond_out[(size_t)b * 512 + tid] = s;
    v1[tid] = qe[(size_t)b * 512 + tid] + s;
  }
  __syncthreads();
  {
    float s0 = 0.f, s1 = 0.f, s2 = 0.f, s3 = 0.f;
#pragma unroll 4
    for (int k = 0; k < 512; k += 4) {
      s0 = fmaf(v1[k], WqT[(size_t)k * 512 + tid], s0);
      s1 = fmaf(v1[k + 1], WqT[(size_t)(k + 1) * 512 + tid], s1);
      s2 = fmaf(v1[k + 2], WqT[(size_t)(k + 2) * 512 + tid], s2);
      s3 = fmaf(v1[k + 3], WqT[(size_t)(k + 3) * 512 + tid], s3);
    }
    v2[tid] = (s0 + s1) + (s2 + s3);
  }
  __syncthreads();
  {
    float s0 = 0.f, s1 = 0.f, s2 = 0.f, s3 = 0.f;
#pragma unroll 4
    for (int d = 0; d < 512; d += 4) {
      s0 = fmaf(v2[d], Wk[(size_t)d * 512 + tid], s0);
      s1 = fmaf(v2[d + 1], Wk[(size_t)(d + 1) * 512 + tid], s1);
      s2 = fmaf(v2[d + 2], Wk[(size_t)(d + 2) * 512 + tid], s2);
      s3 = fmaf(v2[d + 3], Wk[(size_t)(d + 3) * 512 + tid], s3);
    }
    float qkv = (s0 + s1) + (s2 + s3);
    qk_out[(size_t)b * 512 + tid] = qkv;
    float p = wave_sum64(qkv * v0[tid]);
    if ((tid & 63) == 0) rd[tid >> 6] = p;
  }
  __syncthreads();
  if (tid == 0) {
    float c = 0.f;
#pragma unroll
    for (int w = 0; w < 8; ++w) c += rd[w];
    cb_out[b] = c;
  }
}

// ---------------- B: fused back chain, one block per batch ----------------
__global__ __launch_bounds__(512) void back_kernel(
    const float* __restrict__ spart, const float* __restrict__ cond,
    const float* __restrict__ WvT, const float* __restrict__ WpT, const float* __restrict__ bp,
    const float* __restrict__ Wd1aT, const float* __restrict__ bd1, float* __restrict__ Abuf) {
  __shared__ __attribute__((aligned(16))) float v0[512], v1[512];
  const int b = blockIdx.x, tid = threadIdx.x;
  {
    float s = cond[(size_t)b * 512 + tid];
#pragma unroll
    for (int q = 0; q < 8; ++q) s += spart[((size_t)b * 8 + q) * 512 + tid];
    v0[tid] = s;
  }
  __syncthreads();
  {
    float s0 = 0.f, s1 = 0.f, s2 = 0.f, s3 = 0.f;
#pragma unroll 4
    for (int k = 0; k < 512; k += 4) {
      s0 = fmaf(v0[k], WvT[(size_t)k * 512 + tid], s0);
      s1 = fmaf(v0[k + 1], WvT[(size_t)(k + 1) * 512 + tid], s1);
      s2 = fmaf(v0[k + 2], WvT[(size_t)(k + 2) * 512 + tid], s2);
      s3 = fmaf(v0[k + 3], WvT[(size_t)(k + 3) * 512 + tid], s3);
    }
    v1[tid] = (s0 + s1) + (s2 + s3);
  }
  __syncthreads();
  {
    float s0 = 0.f, s1 = 0.f, s2 = 0.f, s3 = 0.f;
#pragma unroll 4
    for (int k = 0; k < 512; k += 4) {
      s0 = fmaf(v1[k], WpT[(size_t)k * 512 + tid], s0);
      s1 = fmaf(v1[k + 1], WpT[(size_t)(k + 1) * 512 + tid], s1);
      s2 = fmaf(v1[k + 2], WpT[(size_t)(k + 2) * 512 + tid], s2);
      s3 = fmaf(v1[k + 3], WpT[(size_t)(k + 3) * 512 + tid], s3);
    }
    v0[tid] = (s0 + s1) + (s2 + s3) + bp[tid];
  }
  __syncthreads();
  {
    float a0 = 0.f, a1 = 0.f, b0 = 0.f, b1 = 0.f;
#pragma unroll 2
    for (int k = 0; k < 512; k += 2) {
      float x0 = v0[k], x1 = v0[k + 1];
      a0 = fmaf(x0, Wd1aT[(size_t)k * 1024 + tid], a0);
      a1 = fmaf(x1, Wd1aT[(size_t)(k + 1) * 1024 + tid], a1);
      b0 = fmaf(x0, Wd1aT[(size_t)k * 1024 + 512 + tid], b0);
      b1 = fmaf(x1, Wd1aT[(size_t)(k + 1) * 1024 + 512 + tid], b1);
    }
    Abuf[(size_t)b * 1024 + tid] = a0 + a1 + bd1[tid];
    Abuf[(size_t)b * 1024 + 512 + tid] = b0 + b1 + bd1[512 + tid];
  }
}

// ---------------- K3: logits (fp32 dot pass over te; optional bf16 te emit) ----------------
__global__ __launch_bounds__(256) void logits_kernel(
    const float* __restrict__ te, const float* __restrict__ qk,
    const float* __restrict__ constb, const float* __restrict__ x,
    float* __restrict__ logits, unsigned short* __restrict__ te16, int w16) {
  const int wave = threadIdx.x >> 6, lane = threadIdx.x & 63;
  const size_t r = (size_t)blockIdx.x * 4 + wave;
  const int b = (int)(r >> 10);
  const float4* t4 = (const float4*)(te + r * 512);
  const float4* q4 = (const float4*)(qk + (size_t)b * 512);
  float4 a0 = t4[lane], a1 = t4[lane + 64];
  float4 c0 = q4[lane], c1 = q4[lane + 64];
  float s = a0.x * c0.x + a0.y * c0.y + a0.z * c0.z + a0.w * c0.w +
            a1.x * c1.x + a1.y * c1.y + a1.z * c1.z + a1.w * c1.w;
  s = wave_sum64(s);
  if (w16) {
    ushort4 h0 = make_ushort4(f2bf(a0.x), f2bf(a0.y), f2bf(a0.z), f2bf(a0.w));
    ushort4 h1 = make_ushort4(f2bf(a1.x), f2bf(a1.y), f2bf(a1.z), f2bf(a1.w));
    *(ushort4*)(te16 + r * 512 + lane * 4) = h0;
    *(ushort4*)(te16 + r * 512 + 256 + lane * 4) = h1;
  }
  if (lane == 0) logits[r] = s + constb[b] + x[r];
}

// ---------------- K4: softmax per batch; also init out = w + bd2 ----------------
__global__ __launch_bounds__(256) void softmax_kernel(
    const float* __restrict__ logits, const float* __restrict__ bd2,
    float* __restrict__ weight, float* __restrict__ out) {
  __shared__ float sm[4];
  const int b = blockIdx.x, tid = threadIdx.x;
  const int wave = tid >> 6, lane = tid & 63;
  float4 l4 = ((const float4*)(logits + (size_t)b * 1024))[tid];
  float m = fmaxf(fmaxf(l4.x, l4.y), fmaxf(l4.z, l4.w));
#pragma unroll
  for (int o = 32; o; o >>= 1) m = fmaxf(m, __shfl_xor(m, o, 64));
  if (lane == 0) sm[wave] = m;
  __syncthreads();
  float M = fmaxf(fmaxf(sm[0], sm[1]), fmaxf(sm[2], sm[3]));
  __syncthreads();
  float e0 = expf(l4.x - M), e1 = expf(l4.y - M), e2 = expf(l4.z - M), e3 = expf(l4.w - M);
  float ssum = wave_sum64(e0 + e1 + e2 + e3);
  if (lane == 0) sm[wave] = ssum;
  __syncthreads();
  float inv = 1.f / (sm[0] + sm[1] + sm[2] + sm[3]);
  float c = bd2[0];
  float4 w4 = make_float4(e0 * inv, e1 * inv, e2 * inv, e3 * inv);
  ((float4*)(weight + (size_t)b * 1024))[tid] = w4;
  ((float4*)(out + (size_t)b * 1024))[tid] = make_float4(w4.x + c, w4.y + c, w4.z + c, w4.w + c);
}

// ---------------- K5a: spart[(b,vq)][d] = sum_{v in chunk} w * te  (fp32 input) ----------------
__global__ __launch_bounds__(256) void wsum32_kernel(const float* __restrict__ te,
                                                     const float* __restrict__ weight,
                                                     float* __restrict__ spart) {
  __shared__ float wl[128];
  const int b = blockIdx.x >> 3, vq = blockIdx.x & 7;
  const int tid = threadIdx.x;
  if (tid < 128) wl[tid] = weight[(size_t)b * 1024 + vq * 128 + tid];
  __syncthreads();
  const float* tb = te + ((size_t)b * 1024 + (size_t)vq * 128) * 512;
  float s0 = 0.f, s1 = 0.f;
#pragma unroll 4
  for (int v = 0; v < 128; ++v) {
    float w = wl[v];
    s0 += w * tb[(size_t)v * 512 + tid];
    s1 += w * tb[(size_t)v * 512 + 256 + tid];
  }
  spart[(size_t)blockIdx.x * 512 + tid] = s0;
  spart[(size_t)blockIdx.x * 512 + 256 + tid] = s1;
}

// ---------------- K5a': same from bf16 te ----------------
__global__ __launch_bounds__(256) void wsum16_kernel(const unsigned short* __restrict__ te16,
                                                     const float* __restrict__ weight,
                                                     float* __restrict__ spart) {
  __shared__ float wl[128];
  __shared__ float red[4][512];
  const int b = blockIdx.x >> 3, vq = blockIdx.x & 7;
  const int tid = threadIdx.x;
  if (tid < 128) wl[tid] = weight[(size_t)b * 1024 + vq * 128 + tid];
  __syncthreads();
  const int g = tid & 63, vh = tid >> 6;
  const unsigned short* base =
      te16 + ((size_t)b * 1024 + vq * 128 + vh * 32) * 512 + g * 8;
  float acc[8] = {};
  for (int v = 0; v < 32; ++v) {
    float w = wl[vh * 32 + v];
    ushort8_t h = *(const ushort8_t*)(base + (size_t)v * 512);
#pragma unroll
    for (int i = 0; i < 8; ++i) acc[i] += w * bf2f(h[i]);
  }
#pragma unroll
  for (int i = 0; i < 8; ++i) red[vh][g * 8 + i] = acc[i];
  __syncthreads();
  for (int d = tid; d < 512; d += 256)
    spart[(size_t)blockIdx.x * 512 + d] =
        red[0][d] + red[1][d] + red[2][d] + red[3][d];
}

// ---------------- K6: decoder GEMM + fused epilogue (v10) ----------------
// 2048 blocks x 512 thr (8 waves). Block: 64 rows x 1024 cols (2 passes of 512).
// Wave w owns cols [w*64, +64) per pass: acc[4m][4n] fx4 = 64 regs (AGPR).
// A (te16) in LDS once (64KB, XOR swizzle); read by all waves (dup x8).
// B (W) global->reg wave-private dbuf, fragment-major 4KB/K-step, coalesced.
// NO barriers in the K-loop. Epilogue scalars from LDS. Arch-VGPR live ~100.
#define GLD16(g, l)                                                              \
  __builtin_amdgcn_global_load_lds((const __attribute__((address_space(1))) void*)(g), \
                                   (__attribute__((address_space(3))) void*)(l), 16, 0, 0)

template <int USE16>
__global__ __launch_bounds__(512, 2) void decoder_kernel(
    const float* __restrict__ te, const unsigned short* __restrict__ te16,
    const unsigned short* __restrict__ wsW, const float* __restrict__ A,
    const float* __restrict__ Wd2, float* __restrict__ out) {
  extern __shared__ char lds[];   // A 65536 | av 4096 | wv 4096 | red 2048 = 75776
  float* av_lds = (float*)(lds + 65536);
  float* wv_lds = (float*)(lds + 69632);
  float* red = (float*)(lds + 73728);

  const int tid = threadIdx.x;
  const int wave = tid >> 6, lane = tid & 63;
  const int lhi = lane >> 4, llo = lane & 15;
  const size_t row0 = (size_t)blockIdx.x * 64;
  const int b = (int)(blockIdx.x >> 4);

  // ---- stage A (64 rows x 1KB bf16, XOR swizzle byte^=(r&7)<<4) ----
  if (USE16) {
    const char* src = (const char*)te16 + row0 * 1024;
#pragma unroll
    for (int it = 0; it < 8; ++it) {
      const int r = it * 8 + wave;  // r&7 == wave
      GLD16(src + (size_t)r * 1024 + ((lane * 16) ^ (wave << 4)), lds + r * 1024);
    }
  } else {
    const float* src = te + row0 * 512;
#pragma unroll
    for (int it = 0; it < 8; ++it) {
      int u = it * 512 + tid;  // 4096 16B-units
      int r = u >> 6, c = u & 63;
      const float4* s = (const float4*)(src + (size_t)r * 512 + c * 8);
      float4 f0 = s[0], f1 = s[1];
      ushort4 h0 = make_ushort4(f2bf(f0.x), f2bf(f0.y), f2bf(f0.z), f2bf(f0.w));
      ushort4 h1 = make_ushort4(f2bf(f1.x), f2bf(f1.y), f2bf(f1.z), f2bf(f1.w));
      char* d = lds + r * 1024 + ((c * 16) ^ ((r & 7) << 4));
      *(ushort4*)d = h0;
      *(ushort4*)(d + 8) = h1;
    }
  }
  // ---- stage av/wv ----
  {
    const float* A_g = A + (size_t)b * 1024;
    av_lds[tid] = A_g[tid];        av_lds[tid + 512] = A_g[tid + 512];
    wv_lds[tid] = Wd2[tid];        wv_lds[tid + 512] = Wd2[tid + 512];
  }
  __syncthreads();  // drains vmcnt+lgkmcnt (incl. global_load_lds)

  // ---- main loop: 2 passes x 16 K32-steps, zero barriers ----
  const int xr = (llo & 7) << 4;
  const char* abase = lds + llo * 1024;  // + m*16384 + ((s*64+lhi*16)^xr)
  const char* wb0 = (const char*)wsW + ((size_t)wave << 16) + lane * 16;  // + p*524288 + s*4096 + n*1024

  float pacc[4][4] = {};
  fx4_t acc[4][4];
  const fx4_t zf = {0.f, 0.f, 0.f, 0.f};
  bhalf8_t bw0[4], bw1[4];

#pragma unroll
  for (int p = 0; p < 2; ++p) {
    const char* wb = wb0 + (size_t)p * 524288;

    auto issue = [&](bhalf8_t (&dst)[4], int s) {
      const char* q = wb + s * 4096;
#pragma unroll
      for (int n = 0; n < 4; ++n) dst[n] = *(const bhalf8_t*)(q + n * 1024);
    };
    auto body = [&](bhalf8_t (&bw)[4], int s) {
      const int off = (s * 64 + lhi * 16) ^ xr;
      bhalf8_t a0 = *(const bhalf8_t*)(abase + off);
      bhalf8_t a1 = *(const bhalf8_t*)(abase + 16384 + off);
      bhalf8_t a2 = *(const bhalf8_t*)(abase + 32768 + off);
      bhalf8_t a3 = *(const bhalf8_t*)(abase + 49152 + off);
#pragma unroll
      for (int n = 0; n < 4; ++n) {
        acc[0][n] = __builtin_amdgcn_mfma_f32_16x16x32_bf16(a0, bw[n], acc[0][n], 0, 0, 0);
        acc[1][n] = __builtin_amdgcn_mfma_f32_16x16x32_bf16(a1, bw[n], acc[1][n], 0, 0, 0);
        acc[2][n] = __builtin_amdgcn_mfma_f32_16x16x32_bf16(a2, bw[n], acc[2][n], 0, 0, 0);
        acc[3][n] = __builtin_amdgcn_mfma_f32_16x16x32_bf16(a3, bw[n], acc[3][n], 0, 0, 0);
      }
    };

#pragma unroll
    for (int m = 0; m < 4; ++m)
#pragma unroll
      for (int n = 0; n < 4; ++n) acc[m][n] = zf;

    issue(bw0, 0);
    issue(bw1, 1);
#pragma unroll
    for (int kp = 0; kp < 8; ++kp) {
      body(bw0, 2 * kp);
      if (2 * kp + 2 < 16) issue(bw0, 2 * kp + 2);
      body(bw1, 2 * kp + 1);
      if (2 * kp + 3 < 16) issue(bw1, 2 * kp + 3);
    }

    // ---- epilogue for this pass (LDS scalars; pacc in regs, accumulates) ----
#pragma unroll
    for (int n = 0; n < 4; ++n) {
      const int j = p * 512 + wave * 64 + n * 16 + llo;
      const float av = av_lds[j];
      const float wvv = wv_lds[j];
#pragma unroll
      for (int m = 0; m < 4; ++m)
#pragma unroll
        for (int rg = 0; rg < 4; ++rg)
          pacc[m][rg] += fmaxf(acc[m][n][rg] + av, 0.f) * wvv;
    }
  }

  // ---- cross-lane + cross-wave reduction ----
#pragma unroll
  for (int m = 0; m < 4; ++m)
#pragma unroll
    for (int rg = 0; rg < 4; ++rg) {
      float sv = pacc[m][rg];
      sv += __shfl_xor(sv, 1, 64);
      sv += __shfl_xor(sv, 2, 64);
      sv += __shfl_xor(sv, 4, 64);
      sv += __shfl_xor(sv, 8, 64);
      if (llo == 0) red[wave * 64 + m * 16 + lhi * 4 + rg] = sv;
    }
  __syncthreads();
  if (tid < 64) {
    float s = 0.f;
#pragma unroll
    for (int w = 0; w < 8; ++w) s += red[w * 64 + tid];
    out[row0 + tid] += s;  // out pre-initialized to w + bd2; rows exclusive per block
  }
}

// ---------------- launch ----------------
extern "C" void kernel_launch(void* const* d_in, const int* in_sizes, int n_in,
                              void* d_out, int out_size, void* d_ws, size_t ws_size,
                              hipStream_t stream) {
  const float* x = (const float*)d_in[0];
  const int* tsteps = (const int*)d_in[1];
  const float* qe = (const float*)d_in[2];
  const float* te = (const float*)d_in[3];
  const float* Wq = (const float*)d_in[4];
  const float* Wk = (const float*)d_in[5];
  const float* Wv = (const float*)d_in[6];
  const float* Wp = (const float*)d_in[7];
  const float* bp = (const float*)d_in[8];
  const float* Wt1 = (const float*)d_in[9];
  const float* bt1 = (const float*)d_in[10];
  const float* Wt2 = (const float*)d_in[11];
  const float* bt2 = (const float*)d_in[12];
  const float* Wd1 = (const float*)d_in[13];
  const float* bd1 = (const float*)d_in[14];
  const float* Wd2 = (const float*)d_in[15];
  const float* bd2 = (const float*)d_in[16];
  float* out = (float*)d_out;

  char* ws = (char*)d_ws;
  unsigned short* wsW = (unsigned short*)(ws + 0);     // 1 MB
  float* Wt1T = (float*)(ws + 1048576);                // 1 MB each
  float* Wt2T = (float*)(ws + 2097152);
  float* WqT = (float*)(ws + 3145728);
  float* WvT = (float*)(ws + 4194304);
  float* WpT = (float*)(ws + 5242880);
  float* Wd1aT = (float*)(ws + 6291456);               // 2 MB [512][1024]
  float* cond = (float*)(ws + 8388608);                // 256 KB
  float* qk = (float*)(ws + 8650752);
  float* cb = (float*)(ws + 9961472);                  // 4 KB slot
  float* logits = (float*)(ws + 9965568);              // 512 KB
  float* wgt = (float*)(ws + 10489856);                // 512 KB
  float* spart = (float*)(ws + 11014144);              // 2 MB [128*8][512]
  float* Abuf = (float*)(ws + 13111296);               // 512 KB
  const size_t TE16_OFF = 14680064;                    // 14 MB
  const size_t TE16_BYTES = (size_t)128 * 1024 * 512 * 2;  // 128 MB
  unsigned short* te16 = (unsigned short*)(ws + TE16_OFF);
  const int use16 = (ws_size >= TE16_OFF + TE16_BYTES) ? 1 : 0;

  // 1: all weight prep (transposes + decoder W pre-pack)
  prepw_kernel<<<dim3(16, 32, 7), 256, 0, stream>>>(Wt1, Wt2, Wq, Wv, Wp, Wd1,
                                                    Wt1T, Wt2T, WqT, WvT, WpT, Wd1aT, wsW);
  // 2: fused front chain (cond, qk, cb)
  front_kernel<<<128, 512, 0, stream>>>(tsteps, qe, Wt1T, bt1, Wt2T, bt2, WqT, Wk,
                                        cond, qk, cb);
  // 3: logits (+te16 emit)
  logits_kernel<<<32768, 256, 0, stream>>>(te, qk, cb, x, logits, te16, use16);
  // 4: softmax (writes wgt; inits out = w + bd2)
  softmax_kernel<<<128, 256, 0, stream>>>(logits, bd2, wgt, out);
  // 5: weighted te sum partials
  if (use16)
    wsum16_kernel<<<1024, 256, 0, stream>>>(te16, wgt, spart);
  else
    wsum32_kernel<<<1024, 256, 0, stream>>>(te, wgt, spart);
  // 6: fused back chain (new_emb -> A)
  back_kernel<<<128, 512, 0, stream>>>(spart, cond, WvT, WpT, bp, Wd1aT, bd1, Abuf);
  // 7: decoder GEMM + epilogue
  if (use16) {
    (void)hipFuncSetAttribute((const void*)decoder_kernel<1>,
                              hipFuncAttributeMaxDynamicSharedMemorySize, 75776);
    decoder_kernel<1><<<2048, 512, 75776, stream>>>(te, te16, wsW, Abuf, Wd2, out);
  } else {
    (void)hipFuncSetAttribute((const void*)decoder_kernel<0>,
                              hipFuncAttributeMaxDynamicSharedMemorySize, 75776);
    decoder_kernel<0><<<2048, 512, 75776, stream>>>(te, te16, wsW, Abuf, Wd2, out);
  }
}

// Round 11
// 411.984 us; speedup vs baseline: 1.3740x; 1.2986x over previous
//
#include <hip/hip_runtime.h>
#include <hip/hip_bf16.h>

// Diffusion decoder, algebraically factored:
//   cond_b = MLP(pe[t_b]);  q_b = Wq@(qe_b+cond_b);  qk_b = Wk^T q_b
//   logit[b,v] = qk_b . te[b,v] + qk_b.cond_b + x[b,v]       (fp32 pass over te)
//   w = softmax(logit); s_b = sum_v w te[b,v]                (bf16 pass over te)
//   new_emb_b = Wp@(Wv@(s_b+cond_b)) + bp
//   A_b = Wd1[:, :512]@new_emb_b + bd1
//   p[b,v] = Wd2 . relu(A_b + Wd1[:,512:]@te[b,v]) + bd2 + w (bf16 MFMA GEMM, fused epilogue)
//
// v11 decoder: v10 tiling (64x64 wave tile, 4x4 acc in AGPR -> optimal 2MB/block
// LDS read traffic) + v8 staging (B via global_load_lds into a 3x32KB LDS ring,
// stage issued 2 steps ahead, counted vmcnt(4), 1 barrier/step) — fixes v10's
// B-load latency stalls without touching the arch-VGPR budget (~90 live regs).
// LDS = A 64KB + ring 96KB = 160KB, 1 block/CU. av/wv in 16 pinned regs.

typedef __attribute__((ext_vector_type(8))) short bhalf8_t;   // 8 bf16 in 4 VGPRs
typedef __attribute__((ext_vector_type(8))) unsigned short ushort8_t;
typedef __attribute__((ext_vector_type(4))) float fx4_t;

__device__ __forceinline__ unsigned short f2bf(float f) {
  unsigned int u = __float_as_uint(f);
  unsigned int r = (u + 0x7FFFu + ((u >> 16) & 1u)) >> 16;  // RNE
  return (unsigned short)r;
}
__device__ __forceinline__ float bf2f(unsigned short h) {
  return __uint_as_float((unsigned int)h << 16);
}

__device__ __forceinline__ float wave_sum64(float s) {
#pragma unroll
  for (int o = 32; o; o >>= 1) s += __shfl_xor(s, o, 64);
  return s;
}

// ---------------- P: all weight prep in ONE launch ----------------
// z 0..4 : 512x512 transposes (y<16)      z=5 : Wd1[:, :512] -> Wd1aT [512][1024]
// z=6    : convw Wd1[:,512:] -> bf16, stage-major for the v11 B-ring (y<16).
//          16B-unit G: stage = G>>11 (p=stage>>4, ks=stage&15), u = G&2047
//          (w=u>>8, n=(u>>6)&3, l=u&63); holds W[j][512+k..+8],
//          j = p*512 + w*64 + n*16 + (l&15), k = ks*32 + (l>>4)*8.
__global__ __launch_bounds__(256) void prepw_kernel(
    const float* __restrict__ Wt1, const float* __restrict__ Wt2, const float* __restrict__ Wq,
    const float* __restrict__ Wv, const float* __restrict__ Wp, const float* __restrict__ Wd1,
    float* __restrict__ Wt1T, float* __restrict__ Wt2T, float* __restrict__ WqT,
    float* __restrict__ WvT, float* __restrict__ WpT, float* __restrict__ Wd1aT,
    unsigned short* __restrict__ wsW) {
  const int z = blockIdx.z;
  if (z == 6) {
    if (blockIdx.y >= 16) return;
    const int g = (blockIdx.y * 16 + blockIdx.x) * 256 + threadIdx.x;  // 0..65535
    const int l = g & 63;
    const int u = g & 2047;
    const int stg = g >> 11;
    const int p = stg >> 4, ks = stg & 15;
    const int w = (u >> 8) & 7, n = (u >> 6) & 3;
    const int j = p * 512 + w * 64 + n * 16 + (l & 15);
    const int k = ks * 32 + (l >> 4) * 8;
    const float* src = Wd1 + (size_t)j * 1024 + 512 + k;
    float4 f0 = *(const float4*)src;
    float4 f1 = *(const float4*)(src + 4);
    ushort4 h0 = make_ushort4(f2bf(f0.x), f2bf(f0.y), f2bf(f0.z), f2bf(f0.w));
    ushort4 h1 = make_ushort4(f2bf(f1.x), f2bf(f1.y), f2bf(f1.z), f2bf(f1.w));
    ushort4* dst = (ushort4*)((char*)wsW + (size_t)g * 16);
    dst[0] = h0;
    dst[1] = h1;
    return;
  }
  __shared__ float t[32][33];
  const int tx = threadIdx.x & 31, ty = threadIdx.x >> 5;
  const int c0 = blockIdx.x * 32, r0 = blockIdx.y * 32;
  if (z == 5) {  // Wd1 first half: src [1024][1024] cols 0..511 -> dst [512][1024]
    const float* src = Wd1;
    float* dst = Wd1aT;
#pragma unroll
    for (int i = 0; i < 32; i += 8)
      t[ty + i][tx] = src[(size_t)(r0 + ty + i) * 1024 + c0 + tx];
    __syncthreads();
#pragma unroll
    for (int i = 0; i < 32; i += 8)
      dst[(size_t)(c0 + ty + i) * 1024 + r0 + tx] = t[tx][ty + i];
    return;
  }
  if (blockIdx.y >= 16) return;
  const float* src;
  float* dst;
  switch (z) {
    case 0: src = Wt1; dst = Wt1T; break;
    case 1: src = Wt2; dst = Wt2T; break;
    case 2: src = Wq; dst = WqT; break;
    case 3: src = Wv; dst = WvT; break;
    default: src = Wp; dst = WpT; break;
  }
#pragma unroll
  for (int i = 0; i < 32; i += 8)
    t[ty + i][tx] = src[(size_t)(r0 + ty + i) * 512 + c0 + tx];
  __syncthreads();
#pragma unroll
  for (int i = 0; i < 32; i += 8)
    dst[(size_t)(c0 + ty + i) * 512 + r0 + tx] = t[tx][ty + i];
}

// ---------------- F: fused front chain, one block per batch ----------------
__global__ __launch_bounds__(512) void front_kernel(
    const int* __restrict__ timesteps, const float* __restrict__ qe,
    const float* __restrict__ Wt1T, const float* __restrict__ bt1,
    const float* __restrict__ Wt2T, const float* __restrict__ bt2,
    const float* __restrict__ WqT, const float* __restrict__ Wk,
    float* __restrict__ cond_out, float* __restrict__ qk_out, float* __restrict__ cb_out) {
  __shared__ __attribute__((aligned(16))) float v0[512], v1[512], v2[512];
  __shared__ float rd[8];
  const int b = blockIdx.x, tid = threadIdx.x;
  if (tid < 256) {
    const int ts = timesteps[b];
    const float NEG = -9.2103403719761836f / 512.f;  // -ln(10000)/512
    float dv = expf((float)(2 * tid) * NEG);
    float ang = (float)ts * dv;
    v0[2 * tid] = sinf(ang);
    v0[2 * tid + 1] = cosf(ang);
  }
  __syncthreads();
  {
    float s0 = 0.f, s1 = 0.f, s2 = 0.f, s3 = 0.f;
#pragma unroll 4
    for (int k = 0; k < 512; k += 4) {
      s0 = fmaf(v0[k], Wt1T[(size_t)k * 512 + tid], s0);
      s1 = fmaf(v0[k + 1], Wt1T[(size_t)(k + 1) * 512 + tid], s1);
      s2 = fmaf(v0[k + 2], Wt1T[(size_t)(k + 2) * 512 + tid], s2);
      s3 = fmaf(v0[k + 3], Wt1T[(size_t)(k + 3) * 512 + tid], s3);
    }
    float s = (s0 + s1) + (s2 + s3) + bt1[tid];
    s = s / (1.f + expf(-s));  // silu
    v1[tid] = s;
  }
  __syncthreads();
  {
    float s0 = 0.f, s1 = 0.f, s2 = 0.f, s3 = 0.f;
#pragma unroll 4
    for (int k = 0; k < 512; k += 4) {
      s0 = fmaf(v1[k], Wt2T[(size_t)k * 512 + tid], s0);
      s1 = fmaf(v1[k + 1], Wt2T[(size_t)(k + 1) * 512 + tid], s1);
      s2 = fmaf(v1[k + 2], Wt2T[(size_t)(k + 2) * 512 + tid], s2);
      s3 = fmaf(v1[k + 3], Wt2T[(size_t)(k + 3) * 512 + tid], s3);
    }
    float s = (s0 + s1) + (s2 + s3) + bt2[tid];
    v0[tid] = s;
    cond_out[(size_t)b * 512 + tid] = s;
    v1[tid] = qe[(size_t)b * 512 + tid] + s;
  }
  __syncthreads();
  {
    float s0 = 0.f, s1 = 0.f, s2 = 0.f, s3 = 0.f;
#pragma unroll 4
    for (int k = 0; k < 512; k += 4) {
      s0 = fmaf(v1[k], WqT[(size_t)k * 512 + tid], s0);
      s1 = fmaf(v1[k + 1], WqT[(size_t)(k + 1) * 512 + tid], s1);
      s2 = fmaf(v1[k + 2], WqT[(size_t)(k + 2) * 512 + tid], s2);
      s3 = fmaf(v1[k + 3], WqT[(size_t)(k + 3) * 512 + tid], s3);
    }
    v2[tid] = (s0 + s1) + (s2 + s3);
  }
  __syncthreads();
  {
    float s0 = 0.f, s1 = 0.f, s2 = 0.f, s3 = 0.f;
#pragma unroll 4
    for (int d = 0; d < 512; d += 4) {
      s0 = fmaf(v2[d], Wk[(size_t)d * 512 + tid], s0);
      s1 = fmaf(v2[d + 1], Wk[(size_t)(d + 1) * 512 + tid], s1);
      s2 = fmaf(v2[d + 2], Wk[(size_t)(d + 2) * 512 + tid], s2);
      s3 = fmaf(v2[d + 3], Wk[(size_t)(d + 3) * 512 + tid], s3);
    }
    float qkv = (s0 + s1) + (s2 + s3);
    qk_out[(size_t)b * 512 + tid] = qkv;
    float p = wave_sum64(qkv * v0[tid]);
    if ((tid & 63) == 0) rd[tid >> 6] = p;
  }
  __syncthreads();
  if (tid == 0) {
    float c = 0.f;
#pragma unroll
    for (int w = 0; w < 8; ++w) c += rd[w];
    cb_out[b] = c;
  }
}

// ---------------- B: fused back chain, one block per batch ----------------
__global__ __launch_bounds__(512) void back_kernel(
    const float* __restrict__ spart, const float* __restrict__ cond,
    const float* __restrict__ WvT, const float* __restrict__ WpT, const float* __restrict__ bp,
    const float* __restrict__ Wd1aT, const float* __restrict__ bd1, float* __restrict__ Abuf) {
  __shared__ __attribute__((aligned(16))) float v0[512], v1[512];
  const int b = blockIdx.x, tid = threadIdx.x;
  {
    float s = cond[(size_t)b * 512 + tid];
#pragma unroll
    for (int q = 0; q < 8; ++q) s += spart[((size_t)b * 8 + q) * 512 + tid];
    v0[tid] = s;
  }
  __syncthreads();
  {
    float s0 = 0.f, s1 = 0.f, s2 = 0.f, s3 = 0.f;
#pragma unroll 4
    for (int k = 0; k < 512; k += 4) {
      s0 = fmaf(v0[k], WvT[(size_t)k * 512 + tid], s0);
      s1 = fmaf(v0[k + 1], WvT[(size_t)(k + 1) * 512 + tid], s1);
      s2 = fmaf(v0[k + 2], WvT[(size_t)(k + 2) * 512 + tid], s2);
      s3 = fmaf(v0[k + 3], WvT[(size_t)(k + 3) * 512 + tid], s3);
    }
    v1[tid] = (s0 + s1) + (s2 + s3);
  }
  __syncthreads();
  {
    float s0 = 0.f, s1 = 0.f, s2 = 0.f, s3 = 0.f;
#pragma unroll 4
    for (int k = 0; k < 512; k += 4) {
      s0 = fmaf(v1[k], WpT[(size_t)k * 512 + tid], s0);
      s1 = fmaf(v1[k + 1], WpT[(size_t)(k + 1) * 512 + tid], s1);
      s2 = fmaf(v1[k + 2], WpT[(size_t)(k + 2) * 512 + tid], s2);
      s3 = fmaf(v1[k + 3], WpT[(size_t)(k + 3) * 512 + tid], s3);
    }
    v0[tid] = (s0 + s1) + (s2 + s3) + bp[tid];
  }
  __syncthreads();
  {
    float a0 = 0.f, a1 = 0.f, b0 = 0.f, b1 = 0.f;
#pragma unroll 2
    for (int k = 0; k < 512; k += 2) {
      float x0 = v0[k], x1 = v0[k + 1];
      a0 = fmaf(x0, Wd1aT[(size_t)k * 1024 + tid], a0);
      a1 = fmaf(x1, Wd1aT[(size_t)(k + 1) * 1024 + tid], a1);
      b0 = fmaf(x0, Wd1aT[(size_t)k * 1024 + 512 + tid], b0);
      b1 = fmaf(x1, Wd1aT[(size_t)(k + 1) * 1024 + 512 + tid], b1);
    }
    Abuf[(size_t)b * 1024 + tid] = a0 + a1 + bd1[tid];
    Abuf[(size_t)b * 1024 + 512 + tid] = b0 + b1 + bd1[512 + tid];
  }
}

// ---------------- K3: logits (fp32 dot pass over te; optional bf16 te emit) ----------------
__global__ __launch_bounds__(256) void logits_kernel(
    const float* __restrict__ te, const float* __restrict__ qk,
    const float* __restrict__ constb, const float* __restrict__ x,
    float* __restrict__ logits, unsigned short* __restrict__ te16, int w16) {
  const int wave = threadIdx.x >> 6, lane = threadIdx.x & 63;
  const size_t r = (size_t)blockIdx.x * 4 + wave;
  const int b = (int)(r >> 10);
  const float4* t4 = (const float4*)(te + r * 512);
  const float4* q4 = (const float4*)(qk + (size_t)b * 512);
  float4 a0 = t4[lane], a1 = t4[lane + 64];
  float4 c0 = q4[lane], c1 = q4[lane + 64];
  float s = a0.x * c0.x + a0.y * c0.y + a0.z * c0.z + a0.w * c0.w +
            a1.x * c1.x + a1.y * c1.y + a1.z * c1.z + a1.w * c1.w;
  s = wave_sum64(s);
  if (w16) {
    ushort4 h0 = make_ushort4(f2bf(a0.x), f2bf(a0.y), f2bf(a0.z), f2bf(a0.w));
    ushort4 h1 = make_ushort4(f2bf(a1.x), f2bf(a1.y), f2bf(a1.z), f2bf(a1.w));
    *(ushort4*)(te16 + r * 512 + lane * 4) = h0;
    *(ushort4*)(te16 + r * 512 + 256 + lane * 4) = h1;
  }
  if (lane == 0) logits[r] = s + constb[b] + x[r];
}

// ---------------- K4: softmax per batch; also init out = w + bd2 ----------------
__global__ __launch_bounds__(256) void softmax_kernel(
    const float* __restrict__ logits, const float* __restrict__ bd2,
    float* __restrict__ weight, float* __restrict__ out) {
  __shared__ float sm[4];
  const int b = blockIdx.x, tid = threadIdx.x;
  const int wave = tid >> 6, lane = tid & 63;
  float4 l4 = ((const float4*)(logits + (size_t)b * 1024))[tid];
  float m = fmaxf(fmaxf(l4.x, l4.y), fmaxf(l4.z, l4.w));
#pragma unroll
  for (int o = 32; o; o >>= 1) m = fmaxf(m, __shfl_xor(m, o, 64));
  if (lane == 0) sm[wave] = m;
  __syncthreads();
  float M = fmaxf(fmaxf(sm[0], sm[1]), fmaxf(sm[2], sm[3]));
  __syncthreads();
  float e0 = expf(l4.x - M), e1 = expf(l4.y - M), e2 = expf(l4.z - M), e3 = expf(l4.w - M);
  float ssum = wave_sum64(e0 + e1 + e2 + e3);
  if (lane == 0) sm[wave] = ssum;
  __syncthreads();
  float inv = 1.f / (sm[0] + sm[1] + sm[2] + sm[3]);
  float c = bd2[0];
  float4 w4 = make_float4(e0 * inv, e1 * inv, e2 * inv, e3 * inv);
  ((float4*)(weight + (size_t)b * 1024))[tid] = w4;
  ((float4*)(out + (size_t)b * 1024))[tid] = make_float4(w4.x + c, w4.y + c, w4.z + c, w4.w + c);
}

// ---------------- K5a: spart[(b,vq)][d] = sum_{v in chunk} w * te  (fp32 input) ----------------
__global__ __launch_bounds__(256) void wsum32_kernel(const float* __restrict__ te,
                                                     const float* __restrict__ weight,
                                                     float* __restrict__ spart) {
  __shared__ float wl[128];
  const int b = blockIdx.x >> 3, vq = blockIdx.x & 7;
  const int tid = threadIdx.x;
  if (tid < 128) wl[tid] = weight[(size_t)b * 1024 + vq * 128 + tid];
  __syncthreads();
  const float* tb = te + ((size_t)b * 1024 + (size_t)vq * 128) * 512;
  float s0 = 0.f, s1 = 0.f;
#pragma unroll 4
  for (int v = 0; v < 128; ++v) {
    float w = wl[v];
    s0 += w * tb[(size_t)v * 512 + tid];
    s1 += w * tb[(size_t)v * 512 + 256 + tid];
  }
  spart[(size_t)blockIdx.x * 512 + tid] = s0;
  spart[(size_t)blockIdx.x * 512 + 256 + tid] = s1;
}

// ---------------- K5a': same from bf16 te ----------------
__global__ __launch_bounds__(256) void wsum16_kernel(const unsigned short* __restrict__ te16,
                                                     const float* __restrict__ weight,
                                                     float* __restrict__ spart) {
  __shared__ float wl[128];
  __shared__ float red[4][512];
  const int b = blockIdx.x >> 3, vq = blockIdx.x & 7;
  const int tid = threadIdx.x;
  if (tid < 128) wl[tid] = weight[(size_t)b * 1024 + vq * 128 + tid];
  __syncthreads();
  const int g = tid & 63, vh = tid >> 6;
  const unsigned short* base =
      te16 + ((size_t)b * 1024 + vq * 128 + vh * 32) * 512 + g * 8;
  float acc[8] = {};
  for (int v = 0; v < 32; ++v) {
    float w = wl[vh * 32 + v];
    ushort8_t h = *(const ushort8_t*)(base + (size_t)v * 512);
#pragma unroll
    for (int i = 0; i < 8; ++i) acc[i] += w * bf2f(h[i]);
  }
#pragma unroll
  for (int i = 0; i < 8; ++i) red[vh][g * 8 + i] = acc[i];
  __syncthreads();
  for (int d = tid; d < 512; d += 256)
    spart[(size_t)blockIdx.x * 512 + d] =
        red[0][d] + red[1][d] + red[2][d] + red[3][d];
}

// ---------------- K6: decoder GEMM + fused epilogue (v11) ----------------
// 2048 blocks x 512 thr (8 waves). Block: 64 rows x 1024 cols (2 passes of 512),
// wave w owns cols w*64..+64 per pass, acc[4m][4n] in AGPR.
// A (te16) in LDS once (64KB, XOR swizzle). B via global_load_lds into a
// 3x32KB LDS ring: stage g+2 issued at step g (after barrier), vmcnt(4)/step.
#define GLD16(g, l)                                                              \
  __builtin_amdgcn_global_load_lds((const __attribute__((address_space(1))) void*)(g), \
                                   (__attribute__((address_space(3))) void*)(l), 16, 0, 0)

template <int USE16>
__global__ __launch_bounds__(512, 2) void decoder_kernel(
    const float* __restrict__ te, const unsigned short* __restrict__ te16,
    const unsigned short* __restrict__ wsW, const float* __restrict__ A,
    const float* __restrict__ Wd2, float* __restrict__ out) {
  extern __shared__ char lds[];   // A 65536 | B ring 3x32768 = 163840
  char* ring = lds + 65536;

  const int tid = threadIdx.x;
  const int wave = tid >> 6, lane = tid & 63;
  const int lhi = lane >> 4, llo = lane & 15;
  const size_t row0 = (size_t)blockIdx.x * 64;
  const int b = (int)(blockIdx.x >> 4);

  // ---- epilogue scalars -> 16 pinned regs (pin's implied drain keeps the
  //      K-loop vmcnt window pure stage-loads) ----
  float av[2][4], wv[2][4];
  {
    const float* A_g = A + (size_t)b * 1024;
#pragma unroll
    for (int p = 0; p < 2; ++p)
#pragma unroll
      for (int n = 0; n < 4; ++n) {
        const int j = p * 512 + wave * 64 + n * 16 + llo;
        av[p][n] = A_g[j];
        wv[p][n] = Wd2[j];
      }
  }
#pragma unroll
  for (int p = 0; p < 2; ++p)
#pragma unroll
    for (int n = 0; n < 4; ++n) asm volatile("" : "+v"(av[p][n]), "+v"(wv[p][n]));

  // ---- stage A (64 rows x 1KB bf16, XOR swizzle byte^=(r&7)<<4) ----
  if (USE16) {
    const char* src = (const char*)te16 + row0 * 1024;
#pragma unroll
    for (int it = 0; it < 8; ++it) {
      const int r = it * 8 + wave;  // r&7 == wave
      GLD16(src + (size_t)r * 1024 + ((lane * 16) ^ (wave << 4)), lds + r * 1024);
    }
  } else {
    const float* src = te + row0 * 512;
#pragma unroll
    for (int it = 0; it < 8; ++it) {
      int u = it * 512 + tid;  // 4096 16B-units
      int r = u >> 6, c = u & 63;
      const float4* s = (const float4*)(src + (size_t)r * 512 + c * 8);
      float4 f0 = s[0], f1 = s[1];
      ushort4 h0 = make_ushort4(f2bf(f0.x), f2bf(f0.y), f2bf(f0.z), f2bf(f0.w));
      ushort4 h1 = make_ushort4(f2bf(f1.x), f2bf(f1.y), f2bf(f1.z), f2bf(f1.w));
      char* d = lds + r * 1024 + ((c * 16) ^ ((r & 7) << 4));
      *(ushort4*)d = h0;
      *(ushort4*)(d + 8) = h1;
    }
    asm volatile("s_waitcnt vmcnt(0) lgkmcnt(0)" ::: "memory");  // clean window
  }

  // ---- B stage: 32KB slab (stage s) -> ring slot s%3; 4 GLD16/thread ----
  auto stage = [&](int s) {
    const char* src = (const char*)wsW + (size_t)s * 32768 + wave * 1024 + lane * 16;
    char* dst = ring + (s % 3) * 32768 + wave * 1024;  // HW appends lane*16
    GLD16(src, dst);
    GLD16(src + 8192, dst + 8192);
    GLD16(src + 16384, dst + 16384);
    GLD16(src + 24576, dst + 24576);
  };
  stage(0);
  stage(1);

  const int xr = (llo & 7) << 4;
  const char* abase = lds + llo * 1024;  // + m*16384 + ((s*64+lhi*16)^xr)
  fx4_t acc[4][4];
  const fx4_t zf = {0.f, 0.f, 0.f, 0.f};
  float pacc[4][4] = {};

#pragma unroll
  for (int p = 0; p < 2; ++p) {
#pragma unroll
    for (int m = 0; m < 4; ++m)
#pragma unroll
      for (int n = 0; n < 4; ++n) acc[m][n] = zf;
#pragma unroll
    for (int s = 0; s < 16; ++s) {
      const int g = p * 16 + s;
      // stage g done; stage g+1 may remain in flight
      if (g <= 30) asm volatile("s_waitcnt vmcnt(4)" ::: "memory");
      else         asm volatile("s_waitcnt vmcnt(0)" ::: "memory");
      __builtin_amdgcn_s_barrier();
      __builtin_amdgcn_sched_barrier(0);
      if (g <= 29) stage(g + 2);  // slot (g+2)%3: held stage g-1, drained at barrier
      const char* wb = ring + (g % 3) * 32768 + wave * 4096 + lane * 16;
      const int off = (s * 64 + lhi * 16) ^ xr;
      bhalf8_t a0 = *(const bhalf8_t*)(abase + off);
      bhalf8_t a1 = *(const bhalf8_t*)(abase + 16384 + off);
      bhalf8_t a2 = *(const bhalf8_t*)(abase + 32768 + off);
      bhalf8_t a3 = *(const bhalf8_t*)(abase + 49152 + off);
      bhalf8_t b0 = *(const bhalf8_t*)(wb);
      bhalf8_t b1 = *(const bhalf8_t*)(wb + 1024);
      bhalf8_t b2 = *(const bhalf8_t*)(wb + 2048);
      bhalf8_t b3 = *(const bhalf8_t*)(wb + 3072);
#pragma unroll
      for (int m = 0; m < 4; ++m) {
        bhalf8_t am = (m == 0) ? a0 : (m == 1) ? a1 : (m == 2) ? a2 : a3;
        acc[m][0] = __builtin_amdgcn_mfma_f32_16x16x32_bf16(am, b0, acc[m][0], 0, 0, 0);
        acc[m][1] = __builtin_amdgcn_mfma_f32_16x16x32_bf16(am, b1, acc[m][1], 0, 0, 0);
        acc[m][2] = __builtin_amdgcn_mfma_f32_16x16x32_bf16(am, b2, acc[m][2], 0, 0, 0);
        acc[m][3] = __builtin_amdgcn_mfma_f32_16x16x32_bf16(am, b3, acc[m][3], 0, 0, 0);
      }
      if (s == 15) {  // epilogue for pass p (pinned regs only)
#pragma unroll
        for (int n = 0; n < 4; ++n)
#pragma unroll
          for (int m = 0; m < 4; ++m)
#pragma unroll
            for (int rg = 0; rg < 4; ++rg)
              pacc[m][rg] += fmaxf(acc[m][n][rg] + av[p][n], 0.f) * wv[p][n];
      }
    }
  }

  // ---- reduction: ring slot 0 region is drained & dead; reuse as red ----
  float* red = (float*)ring;  // [8 wave][64 row]
#pragma unroll
  for (int m = 0; m < 4; ++m)
#pragma unroll
    for (int rg = 0; rg < 4; ++rg) {
      float sv = pacc[m][rg];
      sv += __shfl_xor(sv, 1, 64);
      sv += __shfl_xor(sv, 2, 64);
      sv += __shfl_xor(sv, 4, 64);
      sv += __shfl_xor(sv, 8, 64);
      if (llo == 0) red[wave * 64 + m * 16 + lhi * 4 + rg] = sv;
    }
  __syncthreads();
  if (tid < 64) {
    float s = 0.f;
#pragma unroll
    for (int w = 0; w < 8; ++w) s += red[w * 64 + tid];
    out[row0 + tid] += s;  // out pre-initialized to w + bd2; rows exclusive per block
  }
}

// ---------------- launch ----------------
extern "C" void kernel_launch(void* const* d_in, const int* in_sizes, int n_in,
                              void* d_out, int out_size, void* d_ws, size_t ws_size,
                              hipStream_t stream) {
  const float* x = (const float*)d_in[0];
  const int* tsteps = (const int*)d_in[1];
  const float* qe = (const float*)d_in[2];
  const float* te = (const float*)d_in[3];
  const float* Wq = (const float*)d_in[4];
  const float* Wk = (const float*)d_in[5];
  const float* Wv = (const float*)d_in[6];
  const float* Wp = (const float*)d_in[7];
  const float* bp = (const float*)d_in[8];
  const float* Wt1 = (const float*)d_in[9];
  const float* bt1 = (const float*)d_in[10];
  const float* Wt2 = (const float*)d_in[11];
  const float* bt2 = (const float*)d_in[12];
  const float* Wd1 = (const float*)d_in[13];
  const float* bd1 = (const float*)d_in[14];
  const float* Wd2 = (const float*)d_in[15];
  const float* bd2 = (const float*)d_in[16];
  float* out = (float*)d_out;

  char* ws = (char*)d_ws;
  unsigned short* wsW = (unsigned short*)(ws + 0);     // 1 MB
  float* Wt1T = (float*)(ws + 1048576);                // 1 MB each
  float* Wt2T = (float*)(ws + 2097152);
  float* WqT = (float*)(ws + 3145728);
  float* WvT = (float*)(ws + 4194304);
  float* WpT = (float*)(ws + 5242880);
  float* Wd1aT = (float*)(ws + 6291456);               // 2 MB [512][1024]
  float* cond = (float*)(ws + 8388608);                // 256 KB
  float* qk = (float*)(ws + 8650752);
  float* cb = (float*)(ws + 9961472);                  // 4 KB slot
  float* logits = (float*)(ws + 9965568);              // 512 KB
  float* wgt = (float*)(ws + 10489856);                // 512 KB
  float* spart = (float*)(ws + 11014144);              // 2 MB [128*8][512]
  float* Abuf = (float*)(ws + 13111296);               // 512 KB
  const size_t TE16_OFF = 14680064;                    // 14 MB
  const size_t TE16_BYTES = (size_t)128 * 1024 * 512 * 2;  // 128 MB
  unsigned short* te16 = (unsigned short*)(ws + TE16_OFF);
  const int use16 = (ws_size >= TE16_OFF + TE16_BYTES) ? 1 : 0;

  // 1: all weight prep (transposes + decoder W pre-pack)
  prepw_kernel<<<dim3(16, 32, 7), 256, 0, stream>>>(Wt1, Wt2, Wq, Wv, Wp, Wd1,
                                                    Wt1T, Wt2T, WqT, WvT, WpT, Wd1aT, wsW);
  // 2: fused front chain (cond, qk, cb)
  front_kernel<<<128, 512, 0, stream>>>(tsteps, qe, Wt1T, bt1, Wt2T, bt2, WqT, Wk,
                                        cond, qk, cb);
  // 3: logits (+te16 emit)
  logits_kernel<<<32768, 256, 0, stream>>>(te, qk, cb, x, logits, te16, use16);
  // 4: softmax (writes wgt; inits out = w + bd2)
  softmax_kernel<<<128, 256, 0, stream>>>(logits, bd2, wgt, out);
  // 5: weighted te sum partials
  if (use16)
    wsum16_kernel<<<1024, 256, 0, stream>>>(te16, wgt, spart);
  else
    wsum32_kernel<<<1024, 256, 0, stream>>>(te, wgt, spart);
  // 6: fused back chain (new_emb -> A)
  back_kernel<<<128, 512, 0, stream>>>(spart, cond, WvT, WpT, bp, Wd1aT, bd1, Abuf);
  // 7: decoder GEMM + epilogue
  if (use16) {
    (void)hipFuncSetAttribute((const void*)decoder_kernel<1>,
                              hipFuncAttributeMaxDynamicSharedMemorySize, 163840);
    decoder_kernel<1><<<2048, 512, 163840, stream>>>(te, te16, wsW, Abuf, Wd2, out);
  } else {
    (void)hipFuncSetAttribute((const void*)decoder_kernel<0>,
                              hipFuncAttributeMaxDynamicSharedMemorySize, 163840);
    decoder_kernel<0><<<2048, 512, 163840, stream>>>(te, te16, wsW, Abuf, Wd2, out);
  }
}